// Round 13
// baseline (134.534 us; speedup 1.0000x reference)
//
#include <hip/hip_runtime.h>
#include <math.h>

#define BB 16
#define VV 778
#define OO 8192
#define GG 32
#define KNN 5
#define THREE_LOG2PI 5.513631199228036f

#define MED3 __builtin_amdgcn_fmed3f

// sorted ascending insert: t[j] = min(t[j], max(t[j-1], s)) == med3(s, t[j-1], t[j])
__device__ __forceinline__ void insert5_med3(float (&t)[KNN], float s) {
    t[4] = MED3(s, t[3], t[4]);
    t[3] = MED3(s, t[2], t[3]);
    t[2] = MED3(s, t[1], t[2]);
    t[1] = MED3(s, t[0], t[1]);
    t[0] = fminf(t[0], s);
}

// merge sorted ascending b[5] into sorted ascending m[5]: 15 ops
__device__ __forceinline__ void merge5_med3(float (&m)[KNN], const float (&b)[KNN]) {
    m[4] = MED3(b[0], m[3], m[4]);
    m[3] = MED3(b[0], m[2], m[3]);
    m[2] = MED3(b[0], m[1], m[2]);
    m[1] = MED3(b[0], m[0], m[1]);
    m[0] = fminf(m[0], b[0]);
    m[4] = MED3(b[1], m[3], m[4]);
    m[3] = MED3(b[1], m[2], m[3]);
    m[2] = MED3(b[1], m[1], m[2]);
    m[1] = fminf(m[1], b[1]);
    m[4] = MED3(b[2], m[3], m[4]);
    m[3] = MED3(b[2], m[2], m[3]);
    m[2] = fminf(m[2], b[2]);
    m[4] = MED3(b[3], m[3], m[4]);
    m[3] = fminf(m[3], b[3]);
    m[4] = fminf(m[4], b[4]);
}

// monotone float->uint key: a<b <=> fkey(a)<fkey(b)
__device__ __forceinline__ unsigned int fkey(float s) {
    unsigned int u = __float_as_uint(s);
    unsigned int m = (u & 0x80000000u) ? 0xFFFFFFFFu : 0x80000000u;
    return u ^ m;
}

// ---------------- Kernel A: two block families ------------------------------
// Single-chunk path (NPTS==CH, the live config): 3 unconditional vertex slots
// (tid, tid+256, tid+512; max 767 < 778) in the barrier-free main loop, then a
// wave-0-only tail pass for vertices 768..777 AFTER the main stores (no
// barrier follows, so waves 1-3 retire immediately - no intra-block stall).
// Multi-chunk fallback keeps the proven 4-slot clamped scheme.
template <int LOGP>
__global__ __launch_bounds__(256) void scan_kernel(
    const float* __restrict__ verts,
    const float* __restrict__ anchor_verts,
    const float* __restrict__ obj_pts,
    const float* __restrict__ contact_gaussians,
    const float* __restrict__ obj_normals,
    const float* __restrict__ init_verts,
    const float* __restrict__ init_anchors,
    int* __restrict__ gid_ws,
    float* __restrict__ active_ws,
    float* __restrict__ segmn,
    float* __restrict__ segmx,
    float* __restrict__ w_ws,
    float* __restrict__ top5,                 // [B][P][KNN][VV]
    unsigned long long* __restrict__ pmin,    // [B][P][VV] (fkey<<32)|idx
    float* __restrict__ out) {
    constexpr int P = 1 << LOGP;
    constexpr int NPTS = OO >> LOGP;
    constexpr int CH = (NPTS < 512) ? NPTS : 512;

    __shared__ float4 tile[CH];
    __shared__ float anc[GG * 4];
    __shared__ float cholb[GG * 10];
    __shared__ unsigned short gidl[VV];
    __shared__ unsigned int smn[GG], smx[GG];

    int tid = threadIdx.x;
    int bid = blockIdx.x;

    if (bid < BB * P) {
        // ================= Family 1: KNN top-5 =============================
        int p = bid & (P - 1);
        int b = bid >> LOGP;
        const float* pb = obj_pts + ((size_t)b * OO + p * NPTS) * 3;
        size_t obase = ((size_t)(b * P + p) * KNN) * VV;

        if constexpr (NPTS == CH) {
            float X[3], Y[3], Z[3];
#pragma unroll
            for (int s = 0; s < 3; ++s) {
                const float* vp = verts + ((size_t)b * VV + tid + s * 256) * 3;
                X[s] = -2.0f * vp[0];
                Y[s] = -2.0f * vp[1];
                Z[s] = -2.0f * vp[2];
            }
            float t[3][KNN];
#pragma unroll
            for (int s = 0; s < 3; ++s)
#pragma unroll
                for (int k = 0; k < KNN; ++k) t[s][k] = INFINITY;

            for (int j = tid; j < CH; j += 256) {
                const float* q = pb + (size_t)j * 3;
                float a0 = q[0], a1 = q[1], a2 = q[2];
                tile[j] = make_float4(a0, a1, a2, a0 * a0 + a1 * a1 + a2 * a2);
            }
            __syncthreads();
#pragma unroll 4
            for (int i = 0; i < CH; ++i) {
                float4 q = tile[i];
#pragma unroll
                for (int s = 0; s < 3; ++s) {
                    float sv = fmaf(X[s], q.x, fmaf(Y[s], q.y, fmaf(Z[s], q.z, q.w)));
                    insert5_med3(t[s], sv);
                }
            }
#pragma unroll
            for (int s = 0; s < 3; ++s) {
#pragma unroll
                for (int k = 0; k < KNN; ++k)
                    top5[obase + (size_t)k * VV + tid + s * 256] = t[s][k];
            }
            // wave-0 tail: vertices 768..777 (no barrier after -> no stall)
            if (tid < 64) {
                int vt = 768 + (tid < 10 ? tid : 9);
                const float* vp = verts + ((size_t)b * VV + vt) * 3;
                float X3 = -2.0f * vp[0];
                float Y3 = -2.0f * vp[1];
                float Z3 = -2.0f * vp[2];
                float t3[KNN];
#pragma unroll
                for (int k = 0; k < KNN; ++k) t3[k] = INFINITY;
#pragma unroll 8
                for (int i = 0; i < CH; ++i) {
                    float4 q = tile[i];
                    float sv = fmaf(X3, q.x, fmaf(Y3, q.y, fmaf(Z3, q.z, q.w)));
                    insert5_med3(t3, sv);
                }
                if (tid < 10) {
#pragma unroll
                    for (int k = 0; k < KNN; ++k)
                        top5[obase + (size_t)k * VV + 768 + tid] = t3[k];
                }
            }
        } else {
            // multi-chunk fallback: 4 clamped slots (R12-proven)
            float X[4], Y[4], Z[4];
#pragma unroll
            for (int s = 0; s < 3; ++s) {
                const float* vp = verts + ((size_t)b * VV + tid + s * 256) * 3;
                X[s] = -2.0f * vp[0];
                Y[s] = -2.0f * vp[1];
                Z[s] = -2.0f * vp[2];
            }
            int v3 = tid + 768;
            bool val3 = v3 < VV;
            {
                int vc = val3 ? v3 : (VV - 1);
                const float* vp = verts + ((size_t)b * VV + vc) * 3;
                X[3] = -2.0f * vp[0];
                Y[3] = -2.0f * vp[1];
                Z[3] = -2.0f * vp[2];
            }
            float t[4][KNN];
#pragma unroll
            for (int s = 0; s < 4; ++s)
#pragma unroll
                for (int k = 0; k < KNN; ++k) t[s][k] = INFINITY;

            for (int c0 = 0; c0 < NPTS; c0 += CH) {
                if (c0 != 0) __syncthreads();
                for (int j = tid; j < CH; j += 256) {
                    const float* q = pb + (size_t)(c0 + j) * 3;
                    float a0 = q[0], a1 = q[1], a2 = q[2];
                    tile[j] = make_float4(a0, a1, a2, a0 * a0 + a1 * a1 + a2 * a2);
                }
                __syncthreads();
#pragma unroll 4
                for (int i = 0; i < CH; ++i) {
                    float4 q = tile[i];
#pragma unroll
                    for (int s = 0; s < 4; ++s) {
                        float sv = fmaf(X[s], q.x, fmaf(Y[s], q.y, fmaf(Z[s], q.z, q.w)));
                        insert5_med3(t[s], sv);
                    }
                }
            }
#pragma unroll
            for (int s = 0; s < 3; ++s) {
#pragma unroll
                for (int k = 0; k < KNN; ++k)
                    top5[obase + (size_t)k * VV + tid + s * 256] = t[s][k];
            }
            if (val3) {
#pragma unroll
                for (int k = 0; k < KNN; ++k)
                    top5[obase + (size_t)k * VV + v3] = t[3][k];
            }
        }
        return;
    }

    // ================= Family 2: NN argmin (+ duties) ======================
    {
        int sub = bid - BB * P;
        int p = sub & (P - 1);
        int b = sub >> LOGP;

        bool wduty = (p == 0);                    // 16 blocks, one per b
        bool aduty = (p == 1 && b == 0);          // 1 block
        if (wduty || aduty) {
            if (tid < GG) {
                float x = init_anchors[tid * 3 + 0];
                float y = init_anchors[tid * 3 + 1];
                float z = init_anchors[tid * 3 + 2];
                anc[tid * 4 + 0] = x; anc[tid * 4 + 1] = y;
                anc[tid * 4 + 2] = z; anc[tid * 4 + 3] = x * x + y * y + z * z;
                smn[tid] = 0x7F800000u;
                smx[tid] = 0u;
                if (wduty) {
                    const float* cg2 = contact_gaussians + ((size_t)b * GG + tid) * 12;
                    const float* av = anchor_verts + ((size_t)b * GG + tid) * 3;
                    float c00 = cg2[3];
                    float c10 = cg2[6], c11 = cg2[7];
                    float c20 = cg2[9], c21 = cg2[10], c22 = cg2[11];
                    float L00 = sqrtf(c00);
                    float L10 = c10 / L00;
                    float L20 = c20 / L00;
                    float L11 = sqrtf(c11 - L10 * L10);
                    float L21 = (c21 - L20 * L10) / L11;
                    float L22 = sqrtf(c22 - L20 * L20 - L21 * L21);
                    float* c = cholb + tid * 10;
                    c[0] = L00; c[1] = L10; c[2] = L11;
                    c[3] = L20; c[4] = L21; c[5] = L22;
                    c[6] = logf(L00) + logf(L11) + logf(L22);
                    c[7] = cg2[0] + av[0];
                    c[8] = cg2[1] + av[1];
                    c[9] = cg2[2] + av[2];
                }
            }
            __syncthreads();
            for (int v = tid; v < VV; v += 256) {
                float x = init_verts[v * 3 + 0];
                float y = init_verts[v * 3 + 1];
                float z = init_verts[v * 3 + 2];
                float vv = x * x + y * y + z * z;
                float best = INFINITY;
                int bg = 0;
                for (int g = 0; g < GG; ++g) {
                    float d2 = vv + anc[g * 4 + 3] -
                               2.0f * (x * anc[g * 4 + 0] + y * anc[g * 4 + 1] + z * anc[g * 4 + 2]);
                    d2 = fmaxf(d2, 0.0f);
                    if (d2 < best) { best = d2; bg = g; }
                }
                gidl[v] = (unsigned short)bg;
                if (aduty) gid_ws[v] = bg;
            }
            __syncthreads();
            if (wduty) {
                for (int v = tid; v < VV; v += 256) {
                    int g = gidl[v];
                    const float* c = cholb + g * 10;
                    const float* vp = verts + ((size_t)b * VV + v) * 3;
                    float d0 = vp[0] - c[7];
                    float d1 = vp[1] - c[8];
                    float d2 = vp[2] - c[9];
                    float y0 = d0 / c[0];
                    float y1 = (d1 - c[1] * y0) / c[2];
                    float y2 = (d2 - c[3] * y0 - c[4] * y1) / c[5];
                    float maha = y0 * y0 + y1 * y1 + y2 * y2;
                    float wv = expf(-0.5f * (maha + THREE_LOG2PI) - c[6]);
                    w_ws[(size_t)b * VV + v] = wv;
                    unsigned int u = __float_as_uint(wv);
                    atomicMin(&smn[g], u);
                    atomicMax(&smx[g], u);
                }
                __syncthreads();
                if (tid < GG) {
                    segmn[b * GG + tid] = __uint_as_float(smn[tid]);
                    segmx[b * GG + tid] = __uint_as_float(smx[tid]);
                }
            }
            if (aduty) {
                if (tid < GG) {
                    int any = 0;
                    for (int bb = 0; bb < BB && !any; ++bb) {
                        for (int c = 0; c < 12; ++c) {
                            if (fabsf(contact_gaussians[((size_t)bb * GG + tid) * 12 + c]) > 1e-9f) {
                                any = 1;
                                break;
                            }
                        }
                    }
                    active_ws[tid] = any ? 1.0f : 0.0f;
                }
                if (tid == 0) { out[0] = 0.0f; out[1] = 0.0f; }
            }
            __syncthreads();
        }

        const float* nbp = obj_normals + ((size_t)b * OO + p * NPTS) * 6;
        size_t pbase = (size_t)(b * P + p) * VV;

        if constexpr (NPTS == CH) {
            float X[3], Y[3], Z[3];
#pragma unroll
            for (int s = 0; s < 3; ++s) {
                const float* vp = verts + ((size_t)b * VV + tid + s * 256) * 3;
                X[s] = -2.0f * vp[0];
                Y[s] = -2.0f * vp[1];
                Z[s] = -2.0f * vp[2];
            }
            float bs[3];
            int bi[3];
#pragma unroll
            for (int s = 0; s < 3; ++s) { bs[s] = INFINITY; bi[s] = 0; }

            for (int j = tid; j < CH; j += 256) {
                const float* r = nbp + (size_t)j * 6;
                float b0 = r[0], b1 = r[1], b2 = r[2];
                tile[j] = make_float4(b0, b1, b2, b0 * b0 + b1 * b1 + b2 * b2);
            }
            __syncthreads();
#pragma unroll 4
            for (int i = 0; i < CH; ++i) {
                float4 n = tile[i];
#pragma unroll
                for (int s = 0; s < 3; ++s) {
                    float u = fmaf(X[s], n.x, fmaf(Y[s], n.y, fmaf(Z[s], n.z, n.w)));
                    if (u < bs[s]) { bs[s] = u; bi[s] = i; }
                }
            }
#pragma unroll
            for (int s = 0; s < 3; ++s) {
                unsigned long long key =
                    ((unsigned long long)fkey(bs[s]) << 32) |
                    (unsigned int)(p * NPTS + bi[s]);
                pmin[pbase + tid + s * 256] = key;
            }
            // wave-0 tail: vertices 768..777
            if (tid < 64) {
                int vt = 768 + (tid < 10 ? tid : 9);
                const float* vp = verts + ((size_t)b * VV + vt) * 3;
                float X3 = -2.0f * vp[0];
                float Y3 = -2.0f * vp[1];
                float Z3 = -2.0f * vp[2];
                float bs3 = INFINITY;
                int bi3 = 0;
#pragma unroll 8
                for (int i = 0; i < CH; ++i) {
                    float4 n = tile[i];
                    float u = fmaf(X3, n.x, fmaf(Y3, n.y, fmaf(Z3, n.z, n.w)));
                    if (u < bs3) { bs3 = u; bi3 = i; }
                }
                if (tid < 10) {
                    unsigned long long key =
                        ((unsigned long long)fkey(bs3) << 32) |
                        (unsigned int)(p * NPTS + bi3);
                    pmin[pbase + 768 + tid] = key;
                }
            }
        } else {
            // multi-chunk fallback: 4 clamped slots
            float X[4], Y[4], Z[4];
#pragma unroll
            for (int s = 0; s < 3; ++s) {
                const float* vp = verts + ((size_t)b * VV + tid + s * 256) * 3;
                X[s] = -2.0f * vp[0];
                Y[s] = -2.0f * vp[1];
                Z[s] = -2.0f * vp[2];
            }
            int v3 = tid + 768;
            bool val3 = v3 < VV;
            {
                int vc = val3 ? v3 : (VV - 1);
                const float* vp = verts + ((size_t)b * VV + vc) * 3;
                X[3] = -2.0f * vp[0];
                Y[3] = -2.0f * vp[1];
                Z[3] = -2.0f * vp[2];
            }
            float bs[4];
            int bi[4];
#pragma unroll
            for (int s = 0; s < 4; ++s) { bs[s] = INFINITY; bi[s] = 0; }

            for (int c0 = 0; c0 < NPTS; c0 += CH) {
                if (c0 != 0) __syncthreads();
                for (int j = tid; j < CH; j += 256) {
                    const float* r = nbp + (size_t)(c0 + j) * 6;
                    float b0 = r[0], b1 = r[1], b2 = r[2];
                    tile[j] = make_float4(b0, b1, b2, b0 * b0 + b1 * b1 + b2 * b2);
                }
                __syncthreads();
#pragma unroll 4
                for (int i = 0; i < CH; ++i) {
                    float4 n = tile[i];
                    int gi = c0 + i;
#pragma unroll
                    for (int s = 0; s < 4; ++s) {
                        float u = fmaf(X[s], n.x, fmaf(Y[s], n.y, fmaf(Z[s], n.z, n.w)));
                        if (u < bs[s]) { bs[s] = u; bi[s] = gi; }
                    }
                }
            }
#pragma unroll
            for (int s = 0; s < 3; ++s) {
                unsigned long long key =
                    ((unsigned long long)fkey(bs[s]) << 32) |
                    (unsigned int)(p * NPTS + bi[s]);
                pmin[pbase + tid + s * 256] = key;
            }
            if (val3) {
                unsigned long long key =
                    ((unsigned long long)fkey(bs[3]) << 32) |
                    (unsigned int)(p * NPTS + bi[3]);
                pmin[pbase + v3] = key;
            }
        }
    }
}

// ---------------- Kernel B: tree merge + weights + reduce ------------------
// grid = BB * 13 blocks of 256. tid = pi*64 + vi.
template <int LOGP>
__global__ __launch_bounds__(256) void finalize_kernel(
    const float* __restrict__ top5,
    const unsigned long long* __restrict__ pmin,
    const float* __restrict__ obj_normals,
    const float* __restrict__ verts,
    const int* __restrict__ gid,
    const float* __restrict__ w,
    const float* __restrict__ segmn,
    const float* __restrict__ segmx,
    const float* __restrict__ active,
    float* __restrict__ out) {
    constexpr int P = 1 << LOGP;
    constexpr int NM = (P + 3) / 4;
    constexpr int NCH = (VV + 63) / 64;

    __shared__ float mt[4][KNN][64];
    __shared__ unsigned long long at[4][64];
    __shared__ float rd[256], rp[256];

    int tid = threadIdx.x;
    int pi = tid >> 6;
    int vi = tid & 63;
    int b = blockIdx.x / NCH;
    int chunk = blockIdx.x - b * NCH;
    int v = chunk * 64 + vi;
    bool valid = v < VV;

    float m[KNN];
#pragma unroll
    for (int k = 0; k < KNN; ++k) m[k] = INFINITY;
    unsigned long long amin = 0xFFFFFFFFFFFFFFFFull;
    if (valid) {
#pragma unroll
        for (int r = 0; r < NM; ++r) {
            int p = pi * NM + r;
            if (p < P) {
                size_t base = ((size_t)(b * P + p) * KNN) * VV + v;
                float t[KNN];
#pragma unroll
                for (int k = 0; k < KNN; ++k) t[k] = top5[base + (size_t)k * VV];
                merge5_med3(m, t);
                unsigned long long a = pmin[(size_t)(b * P + p) * VV + v];
                if (a < amin) amin = a;
            }
        }
    }

#pragma unroll
    for (int k = 0; k < KNN; ++k) mt[pi][k][vi] = m[k];
    at[pi][vi] = amin;
    __syncthreads();

    if (pi < 2) {
        float t[KNN];
#pragma unroll
        for (int k = 0; k < KNN; ++k) t[k] = mt[pi + 2][k][vi];
        merge5_med3(m, t);
#pragma unroll
        for (int k = 0; k < KNN; ++k) mt[pi][k][vi] = m[k];
        unsigned long long a = at[pi + 2][vi];
        if (a < amin) amin = a;
        at[pi][vi] = amin;
    }
    __syncthreads();

    float cd = 0.0f, cp = 0.0f;
    if (pi == 0 && valid) {
        float t[KNN];
#pragma unroll
        for (int k = 0; k < KNN; ++k) t[k] = mt[1][k][vi];
        merge5_med3(m, t);
        unsigned long long a = at[1][vi];
        if (a < amin) amin = a;

        const float* vp = verts + ((size_t)b * VV + v) * 3;
        float vx = vp[0], vy = vp[1], vz = vp[2];
        float vv = vx * vx + vy * vy + vz * vz;

        int g = gid[v];
        float wv = w[(size_t)b * VV + v];
        float mn = segmn[b * GG + g];
        float mx = segmx[b * GG + g];
        float wn = (wv - mn) / (mx - mn);
        float eff = (active[g] != 0.0f && wn > 0.01f) ? wn : 0.0f;
        float sk = 0.0f;
#pragma unroll
        for (int k = 0; k < KNN; ++k) sk += sqrtf(fmaxf(vv + m[k], 0.0f));
        cd = eff * sk;

        int bi = (int)(unsigned int)(amin & 0xFFFFFFFFull);
        const float* row = obj_normals + ((size_t)b * OO + bi) * 6;
        float n0 = row[3], n1 = row[4], n2 = row[5];
        float r0 = row[0] - 0.002f * n0;
        float r1 = row[1] - 0.002f * n1;
        float r2 = row[2] - 0.002f * n2;
        float dp = n0 * (vx - r0) + n1 * (vy - r1) + n2 * (vz - r2);
        cp = fmaxf(-dp, 0.0f);
    }

    rd[tid] = cd;
    rp[tid] = cp;
    __syncthreads();
    for (int s = 128; s > 0; s >>= 1) {
        if (tid < s) {
            rd[tid] += rd[tid + s];
            rp[tid] += rp[tid + s];
        }
        __syncthreads();
    }
    if (tid == 0) {
        atomicAdd(&out[0], rd[0] * (1.0f / ((float)BB * VV * KNN)));
        atomicAdd(&out[1], rp[0] * (1.0f / ((float)BB * VV)));
    }
}

template <int LOGP>
static void launch_all(const float* verts, const float* anchor_verts,
                       const float* obj_pts, const float* contact_gaussians,
                       const float* obj_normals, const float* init_verts,
                       const float* init_anchors, int* gid_ws, float* active_ws,
                       float* segmn, float* segmx, float* w_ws, float* top5,
                       unsigned long long* pmin, float* out, hipStream_t stream) {
    constexpr int P = 1 << LOGP;
    constexpr int NCH = (VV + 63) / 64;
    dim3 block(256);
    hipLaunchKernelGGL((scan_kernel<LOGP>), dim3(BB * 2 * P), block,
                       0, stream, verts, anchor_verts, obj_pts, contact_gaussians,
                       obj_normals, init_verts, init_anchors, gid_ws, active_ws,
                       segmn, segmx, w_ws, top5, pmin, out);
    hipLaunchKernelGGL((finalize_kernel<LOGP>), dim3(BB * NCH), block, 0, stream,
                       top5, pmin, obj_normals, verts, gid_ws, w_ws, segmn,
                       segmx, active_ws, out);
}

extern "C" void kernel_launch(void* const* d_in, const int* in_sizes, int n_in,
                              void* d_out, int out_size, void* d_ws, size_t ws_size,
                              hipStream_t stream) {
    const float* verts = (const float*)d_in[0];
    const float* anchor_verts = (const float*)d_in[1];
    const float* obj_pts = (const float*)d_in[2];
    const float* contact_gaussians = (const float*)d_in[3];
    const float* obj_normals = (const float*)d_in[4];
    const float* init_verts = (const float*)d_in[5];
    const float* init_anchors = (const float*)d_in[6];
    float* out = (float*)d_out;

    char* ws = (char*)d_ws;
    int* gid_ws = (int*)(ws + 0);                       // 778 i  -> 4096
    float* active_ws = (float*)(ws + 4096);             // 32 f   -> 4224
    float* segmn = (float*)(ws + 4224);                 // 512 f  -> 6272
    float* segmx = (float*)(ws + 6272);                 // 512 f  -> 8320
    float* w_ws = (float*)(ws + 8320);                  // 12448 f-> 58112 (pad 58368)
    const size_t base = 58368;

    // P=16 target (balanced families, single-chunk LDS); fall back if ws small
    int logP = 4;
    while (logP > 0) {
        size_t need = base + (size_t)BB * (1 << logP) * VV * (KNN * 4 + 8);
        if (need <= ws_size) break;
        --logP;
    }
    size_t P = (size_t)1 << logP;

    unsigned long long* pmin = (unsigned long long*)(ws + base);
    float* top5 = (float*)(ws + base + (size_t)BB * P * VV * 8);

#define LAUNCH(L)                                                              \
    launch_all<L>(verts, anchor_verts, obj_pts, contact_gaussians,             \
                  obj_normals, init_verts, init_anchors, gid_ws, active_ws,    \
                  segmn, segmx, w_ws, top5, pmin, out, stream)
    switch (logP) {
        case 4: LAUNCH(4); break;
        case 3: LAUNCH(3); break;
        case 2: LAUNCH(2); break;
        case 1: LAUNCH(1); break;
        default: LAUNCH(0); break;
    }
#undef LAUNCH
}

// Round 14
// 128.106 us; speedup vs baseline: 1.0502x; 1.0502x over previous
//
#include <hip/hip_runtime.h>
#include <math.h>

#define BB 16
#define VV 778
#define OO 8192
#define GG 32
#define KNN 5
#define THREE_LOG2PI 5.513631199228036f

#define MED3 __builtin_amdgcn_fmed3f

// sorted ascending insert: t[j] = min(t[j], max(t[j-1], s)) == med3(s, t[j-1], t[j])
__device__ __forceinline__ void insert5_med3(float (&t)[KNN], float s) {
    t[4] = MED3(s, t[3], t[4]);
    t[3] = MED3(s, t[2], t[3]);
    t[2] = MED3(s, t[1], t[2]);
    t[1] = MED3(s, t[0], t[1]);
    t[0] = fminf(t[0], s);
}

// merge sorted ascending b[5] into sorted ascending m[5]: 15 ops
__device__ __forceinline__ void merge5_med3(float (&m)[KNN], const float (&b)[KNN]) {
    m[4] = MED3(b[0], m[3], m[4]);
    m[3] = MED3(b[0], m[2], m[3]);
    m[2] = MED3(b[0], m[1], m[2]);
    m[1] = MED3(b[0], m[0], m[1]);
    m[0] = fminf(m[0], b[0]);
    m[4] = MED3(b[1], m[3], m[4]);
    m[3] = MED3(b[1], m[2], m[3]);
    m[2] = MED3(b[1], m[1], m[2]);
    m[1] = fminf(m[1], b[1]);
    m[4] = MED3(b[2], m[3], m[4]);
    m[3] = MED3(b[2], m[2], m[3]);
    m[2] = fminf(m[2], b[2]);
    m[4] = MED3(b[3], m[3], m[4]);
    m[3] = fminf(m[3], b[3]);
    m[4] = fminf(m[4], b[4]);
}

// monotone float->uint key: a<b <=> fkey(a)<fkey(b)
__device__ __forceinline__ unsigned int fkey(float s) {
    unsigned int u = __float_as_uint(s);
    unsigned int m = (u & 0x80000000u) ? 0xFFFFFFFFu : 0x80000000u;
    return u ^ m;
}

// ---------------- Kernel A: two block families, S=4 vertex slots -----------
// Slots 0-2: v = tid, tid+256, tid+512 (always valid, max 767 < 778).
// Slot 3: v = tid+768, clamped to VV-1 for compute, guarded store.
// All waves execute identical work (clamped redundancy) - measured faster
// than any wave-specialized tail scheme (R11/R13 both regressed).
template <int LOGP>
__global__ __launch_bounds__(256) void scan_kernel(
    const float* __restrict__ verts,
    const float* __restrict__ anchor_verts,
    const float* __restrict__ obj_pts,
    const float* __restrict__ contact_gaussians,
    const float* __restrict__ obj_normals,
    const float* __restrict__ init_verts,
    const float* __restrict__ init_anchors,
    int* __restrict__ gid_ws,
    float* __restrict__ active_ws,
    float* __restrict__ segmn,
    float* __restrict__ segmx,
    float* __restrict__ w_ws,
    float* __restrict__ top5,                 // [B][P][KNN][VV]
    unsigned long long* __restrict__ pmin,    // [B][P][VV] (fkey<<32)|idx
    float* __restrict__ out) {
    constexpr int P = 1 << LOGP;
    constexpr int NPTS = OO >> LOGP;
    constexpr int CH = (NPTS < 512) ? NPTS : 512;

    __shared__ float4 tile[CH];
    __shared__ float anc[GG * 4];
    __shared__ float cholb[GG * 10];
    __shared__ unsigned short gidl[VV];
    __shared__ unsigned int smn[GG], smx[GG];

    int tid = threadIdx.x;
    int bid = blockIdx.x;

    if (bid < BB * P) {
        // ================= Family 1: KNN top-5 =============================
        int p = bid & (P - 1);
        int b = bid >> LOGP;

        float X[4], Y[4], Z[4];
#pragma unroll
        for (int s = 0; s < 3; ++s) {
            const float* vp = verts + ((size_t)b * VV + tid + s * 256) * 3;
            X[s] = -2.0f * vp[0];
            Y[s] = -2.0f * vp[1];
            Z[s] = -2.0f * vp[2];
        }
        int v3 = tid + 768;
        bool val3 = v3 < VV;
        {
            int vc = val3 ? v3 : (VV - 1);
            const float* vp = verts + ((size_t)b * VV + vc) * 3;
            X[3] = -2.0f * vp[0];
            Y[3] = -2.0f * vp[1];
            Z[3] = -2.0f * vp[2];
        }

        float t[4][KNN];
#pragma unroll
        for (int s = 0; s < 4; ++s)
#pragma unroll
            for (int k = 0; k < KNN; ++k) t[s][k] = INFINITY;

        const float* pb = obj_pts + ((size_t)b * OO + p * NPTS) * 3;
        for (int c0 = 0; c0 < NPTS; c0 += CH) {
            if (c0 != 0) __syncthreads();   // block-uniform; multi-chunk only
            for (int j = tid; j < CH; j += 256) {
                const float* q = pb + (size_t)(c0 + j) * 3;
                float a0 = q[0], a1 = q[1], a2 = q[2];
                tile[j] = make_float4(a0, a1, a2, a0 * a0 + a1 * a1 + a2 * a2);
            }
            __syncthreads();
#pragma unroll 4
            for (int i = 0; i < CH; ++i) {
                float4 q = tile[i];
#pragma unroll
                for (int s = 0; s < 4; ++s) {
                    float sv = fmaf(X[s], q.x, fmaf(Y[s], q.y, fmaf(Z[s], q.z, q.w)));
                    insert5_med3(t[s], sv);
                }
            }
        }
        {
            size_t base = ((size_t)(b * P + p) * KNN) * VV;
#pragma unroll
            for (int s = 0; s < 3; ++s) {
#pragma unroll
                for (int k = 0; k < KNN; ++k)
                    top5[base + (size_t)k * VV + tid + s * 256] = t[s][k];
            }
            if (val3) {
#pragma unroll
                for (int k = 0; k < KNN; ++k)
                    top5[base + (size_t)k * VV + v3] = t[3][k];
            }
        }
        return;
    }

    // ================= Family 2: NN argmin (+ duties) ======================
    {
        int sub = bid - BB * P;
        int p = sub & (P - 1);
        int b = sub >> LOGP;

        bool wduty = (p == 0);                    // 16 blocks, one per b
        bool aduty = (p == 1 && b == 0);          // 1 block
        if (wduty || aduty) {
            if (tid < GG) {
                float x = init_anchors[tid * 3 + 0];
                float y = init_anchors[tid * 3 + 1];
                float z = init_anchors[tid * 3 + 2];
                anc[tid * 4 + 0] = x; anc[tid * 4 + 1] = y;
                anc[tid * 4 + 2] = z; anc[tid * 4 + 3] = x * x + y * y + z * z;
                smn[tid] = 0x7F800000u;
                smx[tid] = 0u;
                if (wduty) {
                    const float* cg2 = contact_gaussians + ((size_t)b * GG + tid) * 12;
                    const float* av = anchor_verts + ((size_t)b * GG + tid) * 3;
                    float c00 = cg2[3];
                    float c10 = cg2[6], c11 = cg2[7];
                    float c20 = cg2[9], c21 = cg2[10], c22 = cg2[11];
                    float L00 = sqrtf(c00);
                    float L10 = c10 / L00;
                    float L20 = c20 / L00;
                    float L11 = sqrtf(c11 - L10 * L10);
                    float L21 = (c21 - L20 * L10) / L11;
                    float L22 = sqrtf(c22 - L20 * L20 - L21 * L21);
                    float* c = cholb + tid * 10;
                    c[0] = L00; c[1] = L10; c[2] = L11;
                    c[3] = L20; c[4] = L21; c[5] = L22;
                    c[6] = logf(L00) + logf(L11) + logf(L22);
                    c[7] = cg2[0] + av[0];
                    c[8] = cg2[1] + av[1];
                    c[9] = cg2[2] + av[2];
                }
            }
            __syncthreads();
            for (int v = tid; v < VV; v += 256) {
                float x = init_verts[v * 3 + 0];
                float y = init_verts[v * 3 + 1];
                float z = init_verts[v * 3 + 2];
                float vv = x * x + y * y + z * z;
                float best = INFINITY;
                int bg = 0;
                for (int g = 0; g < GG; ++g) {
                    float d2 = vv + anc[g * 4 + 3] -
                               2.0f * (x * anc[g * 4 + 0] + y * anc[g * 4 + 1] + z * anc[g * 4 + 2]);
                    d2 = fmaxf(d2, 0.0f);
                    if (d2 < best) { best = d2; bg = g; }
                }
                gidl[v] = (unsigned short)bg;
                if (aduty) gid_ws[v] = bg;
            }
            __syncthreads();
            if (wduty) {
                for (int v = tid; v < VV; v += 256) {
                    int g = gidl[v];
                    const float* c = cholb + g * 10;
                    const float* vp = verts + ((size_t)b * VV + v) * 3;
                    float d0 = vp[0] - c[7];
                    float d1 = vp[1] - c[8];
                    float d2 = vp[2] - c[9];
                    float y0 = d0 / c[0];
                    float y1 = (d1 - c[1] * y0) / c[2];
                    float y2 = (d2 - c[3] * y0 - c[4] * y1) / c[5];
                    float maha = y0 * y0 + y1 * y1 + y2 * y2;
                    float wv = expf(-0.5f * (maha + THREE_LOG2PI) - c[6]);
                    w_ws[(size_t)b * VV + v] = wv;
                    unsigned int u = __float_as_uint(wv);
                    atomicMin(&smn[g], u);
                    atomicMax(&smx[g], u);
                }
                __syncthreads();
                if (tid < GG) {
                    segmn[b * GG + tid] = __uint_as_float(smn[tid]);
                    segmx[b * GG + tid] = __uint_as_float(smx[tid]);
                }
            }
            if (aduty) {
                if (tid < GG) {
                    int any = 0;
                    for (int bb = 0; bb < BB && !any; ++bb) {
                        for (int c = 0; c < 12; ++c) {
                            if (fabsf(contact_gaussians[((size_t)bb * GG + tid) * 12 + c]) > 1e-9f) {
                                any = 1;
                                break;
                            }
                        }
                    }
                    active_ws[tid] = any ? 1.0f : 0.0f;
                }
                if (tid == 0) { out[0] = 0.0f; out[1] = 0.0f; }
            }
            __syncthreads();
        }

        float X[4], Y[4], Z[4];
#pragma unroll
        for (int s = 0; s < 3; ++s) {
            const float* vp = verts + ((size_t)b * VV + tid + s * 256) * 3;
            X[s] = -2.0f * vp[0];
            Y[s] = -2.0f * vp[1];
            Z[s] = -2.0f * vp[2];
        }
        int v3 = tid + 768;
        bool val3 = v3 < VV;
        {
            int vc = val3 ? v3 : (VV - 1);
            const float* vp = verts + ((size_t)b * VV + vc) * 3;
            X[3] = -2.0f * vp[0];
            Y[3] = -2.0f * vp[1];
            Z[3] = -2.0f * vp[2];
        }

        float bs[4];
        int bi[4];
#pragma unroll
        for (int s = 0; s < 4; ++s) { bs[s] = INFINITY; bi[s] = 0; }

        const float* nbp = obj_normals + ((size_t)b * OO + p * NPTS) * 6;
        for (int c0 = 0; c0 < NPTS; c0 += CH) {
            if (c0 != 0) __syncthreads();
            for (int j = tid; j < CH; j += 256) {
                const float* r = nbp + (size_t)(c0 + j) * 6;
                float b0 = r[0], b1 = r[1], b2 = r[2];
                tile[j] = make_float4(b0, b1, b2, b0 * b0 + b1 * b1 + b2 * b2);
            }
            __syncthreads();
#pragma unroll 4
            for (int i = 0; i < CH; ++i) {
                float4 n = tile[i];
                int gi = c0 + i;
#pragma unroll
                for (int s = 0; s < 4; ++s) {
                    float u = fmaf(X[s], n.x, fmaf(Y[s], n.y, fmaf(Z[s], n.z, n.w)));
                    if (u < bs[s]) { bs[s] = u; bi[s] = gi; }
                }
            }
        }
#pragma unroll
        for (int s = 0; s < 3; ++s) {
            unsigned long long key =
                ((unsigned long long)fkey(bs[s]) << 32) |
                (unsigned int)(p * NPTS + bi[s]);
            pmin[(size_t)(b * P + p) * VV + tid + s * 256] = key;
        }
        if (val3) {
            unsigned long long key =
                ((unsigned long long)fkey(bs[3]) << 32) |
                (unsigned int)(p * NPTS + bi[3]);
            pmin[(size_t)(b * P + p) * VV + v3] = key;
        }
    }
}

// ---------------- Kernel B: tree merge + weights + reduce ------------------
// grid = BB * 13 blocks of 256. tid = pi*64 + vi.
template <int LOGP>
__global__ __launch_bounds__(256) void finalize_kernel(
    const float* __restrict__ top5,
    const unsigned long long* __restrict__ pmin,
    const float* __restrict__ obj_normals,
    const float* __restrict__ verts,
    const int* __restrict__ gid,
    const float* __restrict__ w,
    const float* __restrict__ segmn,
    const float* __restrict__ segmx,
    const float* __restrict__ active,
    float* __restrict__ out) {
    constexpr int P = 1 << LOGP;
    constexpr int NM = (P + 3) / 4;
    constexpr int NCH = (VV + 63) / 64;

    __shared__ float mt[4][KNN][64];
    __shared__ unsigned long long at[4][64];
    __shared__ float rd[256], rp[256];

    int tid = threadIdx.x;
    int pi = tid >> 6;
    int vi = tid & 63;
    int b = blockIdx.x / NCH;
    int chunk = blockIdx.x - b * NCH;
    int v = chunk * 64 + vi;
    bool valid = v < VV;

    float m[KNN];
#pragma unroll
    for (int k = 0; k < KNN; ++k) m[k] = INFINITY;
    unsigned long long amin = 0xFFFFFFFFFFFFFFFFull;
    if (valid) {
#pragma unroll
        for (int r = 0; r < NM; ++r) {
            int p = pi * NM + r;
            if (p < P) {
                size_t base = ((size_t)(b * P + p) * KNN) * VV + v;
                float t[KNN];
#pragma unroll
                for (int k = 0; k < KNN; ++k) t[k] = top5[base + (size_t)k * VV];
                merge5_med3(m, t);
                unsigned long long a = pmin[(size_t)(b * P + p) * VV + v];
                if (a < amin) amin = a;
            }
        }
    }

#pragma unroll
    for (int k = 0; k < KNN; ++k) mt[pi][k][vi] = m[k];
    at[pi][vi] = amin;
    __syncthreads();

    if (pi < 2) {
        float t[KNN];
#pragma unroll
        for (int k = 0; k < KNN; ++k) t[k] = mt[pi + 2][k][vi];
        merge5_med3(m, t);
#pragma unroll
        for (int k = 0; k < KNN; ++k) mt[pi][k][vi] = m[k];
        unsigned long long a = at[pi + 2][vi];
        if (a < amin) amin = a;
        at[pi][vi] = amin;
    }
    __syncthreads();

    float cd = 0.0f, cp = 0.0f;
    if (pi == 0 && valid) {
        float t[KNN];
#pragma unroll
        for (int k = 0; k < KNN; ++k) t[k] = mt[1][k][vi];
        merge5_med3(m, t);
        unsigned long long a = at[1][vi];
        if (a < amin) amin = a;

        const float* vp = verts + ((size_t)b * VV + v) * 3;
        float vx = vp[0], vy = vp[1], vz = vp[2];
        float vv = vx * vx + vy * vy + vz * vz;

        int g = gid[v];
        float wv = w[(size_t)b * VV + v];
        float mn = segmn[b * GG + g];
        float mx = segmx[b * GG + g];
        float wn = (wv - mn) / (mx - mn);
        float eff = (active[g] != 0.0f && wn > 0.01f) ? wn : 0.0f;
        float sk = 0.0f;
#pragma unroll
        for (int k = 0; k < KNN; ++k) sk += sqrtf(fmaxf(vv + m[k], 0.0f));
        cd = eff * sk;

        int bi = (int)(unsigned int)(amin & 0xFFFFFFFFull);
        const float* row = obj_normals + ((size_t)b * OO + bi) * 6;
        float n0 = row[3], n1 = row[4], n2 = row[5];
        float r0 = row[0] - 0.002f * n0;
        float r1 = row[1] - 0.002f * n1;
        float r2 = row[2] - 0.002f * n2;
        float dp = n0 * (vx - r0) + n1 * (vy - r1) + n2 * (vz - r2);
        cp = fmaxf(-dp, 0.0f);
    }

    rd[tid] = cd;
    rp[tid] = cp;
    __syncthreads();
    for (int s = 128; s > 0; s >>= 1) {
        if (tid < s) {
            rd[tid] += rd[tid + s];
            rp[tid] += rp[tid + s];
        }
        __syncthreads();
    }
    if (tid == 0) {
        atomicAdd(&out[0], rd[0] * (1.0f / ((float)BB * VV * KNN)));
        atomicAdd(&out[1], rp[0] * (1.0f / ((float)BB * VV)));
    }
}

template <int LOGP>
static void launch_all(const float* verts, const float* anchor_verts,
                       const float* obj_pts, const float* contact_gaussians,
                       const float* obj_normals, const float* init_verts,
                       const float* init_anchors, int* gid_ws, float* active_ws,
                       float* segmn, float* segmx, float* w_ws, float* top5,
                       unsigned long long* pmin, float* out, hipStream_t stream) {
    constexpr int P = 1 << LOGP;
    constexpr int NCH = (VV + 63) / 64;
    dim3 block(256);
    hipLaunchKernelGGL((scan_kernel<LOGP>), dim3(BB * 2 * P), block,
                       0, stream, verts, anchor_verts, obj_pts, contact_gaussians,
                       obj_normals, init_verts, init_anchors, gid_ws, active_ws,
                       segmn, segmx, w_ws, top5, pmin, out);
    hipLaunchKernelGGL((finalize_kernel<LOGP>), dim3(BB * NCH), block, 0, stream,
                       top5, pmin, obj_normals, verts, gid_ws, w_ws, segmn,
                       segmx, active_ws, out);
}

extern "C" void kernel_launch(void* const* d_in, const int* in_sizes, int n_in,
                              void* d_out, int out_size, void* d_ws, size_t ws_size,
                              hipStream_t stream) {
    const float* verts = (const float*)d_in[0];
    const float* anchor_verts = (const float*)d_in[1];
    const float* obj_pts = (const float*)d_in[2];
    const float* contact_gaussians = (const float*)d_in[3];
    const float* obj_normals = (const float*)d_in[4];
    const float* init_verts = (const float*)d_in[5];
    const float* init_anchors = (const float*)d_in[6];
    float* out = (float*)d_out;

    char* ws = (char*)d_ws;
    int* gid_ws = (int*)(ws + 0);                       // 778 i  -> 4096
    float* active_ws = (float*)(ws + 4096);             // 32 f   -> 4224
    float* segmn = (float*)(ws + 4224);                 // 512 f  -> 6272
    float* segmx = (float*)(ws + 6272);                 // 512 f  -> 8320
    float* w_ws = (float*)(ws + 8320);                  // 12448 f-> 58112 (pad 58368)
    const size_t base = 58368;

    // P=16 target (balanced families, single-chunk LDS); fall back if ws small
    int logP = 4;
    while (logP > 0) {
        size_t need = base + (size_t)BB * (1 << logP) * VV * (KNN * 4 + 8);
        if (need <= ws_size) break;
        --logP;
    }
    size_t P = (size_t)1 << logP;

    unsigned long long* pmin = (unsigned long long*)(ws + base);
    float* top5 = (float*)(ws + base + (size_t)BB * P * VV * 8);

#define LAUNCH(L)                                                              \
    launch_all<L>(verts, anchor_verts, obj_pts, contact_gaussians,             \
                  obj_normals, init_verts, init_anchors, gid_ws, active_ws,    \
                  segmn, segmx, w_ws, top5, pmin, out, stream)
    switch (logP) {
        case 4: LAUNCH(4); break;
        case 3: LAUNCH(3); break;
        case 2: LAUNCH(2); break;
        case 1: LAUNCH(1); break;
        default: LAUNCH(0); break;
    }
#undef LAUNCH
}